// Round 12
// baseline (169.938 us; speedup 1.0000x reference)
//
#include <hip/hip_runtime.h>
#include <hip/hip_bf16.h>

#define H_ 8
#define D_ 64
#define IN_ 512
#define B_ 4
#define N_ 2048
#define TOK_ (B_*N_)
// softmax in exp2 domain: scale * log2(e) (folded into Q at projection time)
#define CLOG2_ 0.18033688011112042f

typedef __attribute__((ext_vector_type(8))) short short8;
typedef __attribute__((ext_vector_type(4))) short bs4;
typedef __attribute__((ext_vector_type(4))) float f32x4;

__device__ __forceinline__ unsigned short f2bf(float f) {
  unsigned int u = __float_as_uint(f);
  u += 0x7FFFu + ((u >> 16) & 1u);
  return (unsigned short)(u >> 16);
}

// packed converts: v_cvt_pk_bf16_f32
__device__ __forceinline__ short8 cvt8(const float4 a, const float4 b) {
  union { short8 v; __hip_bfloat162 h[4]; } z;
  z.h[0] = __float22bfloat162_rn(make_float2(a.x, a.y));
  z.h[1] = __float22bfloat162_rn(make_float2(a.z, a.w));
  z.h[2] = __float22bfloat162_rn(make_float2(b.x, b.y));
  z.h[3] = __float22bfloat162_rn(make_float2(b.z, b.w));
  return z.v;
}

__device__ __forceinline__ bs4 pack4(float a, float b, float c, float d) {
  union { bs4 v; __hip_bfloat162 h[2]; } z;
  z.h[0] = __float22bfloat162_rn(make_float2(a, b));
  z.h[1] = __float22bfloat162_rn(make_float2(c, d));
  return z.v;
}

// async global->LDS, 16B per lane; dest = wave-uniform base + lane*16
__device__ __forceinline__ void gld16(const unsigned short* g, unsigned short* l) {
  __builtin_amdgcn_global_load_lds(
      (const __attribute__((address_space(1))) void*)g,
      (__attribute__((address_space(3))) void*)l, 16, 0, 0);
}

// ---------------------------------------------------------------------------
// Kernel 0: merged fp32 -> bf16 convert (x, Wq, Wkv, Wo) in ONE launch.
// ---------------------------------------------------------------------------
__global__ __launch_bounds__(256) void conv_all_kernel(
    const float* __restrict__ x, const float* __restrict__ Wq,
    const float* __restrict__ Wkv, const float* __restrict__ Wo,
    unsigned short* __restrict__ xbf, unsigned short* __restrict__ wbf,
    unsigned short* __restrict__ wobf)
{
  const int b = blockIdx.x;
  const float* src;
  unsigned short* dst;
  size_t base;
  if (b < 2048)      { src = x;   dst = xbf;             base = (size_t)b * 2048; }
  else if (b < 2176) { src = Wq;  dst = wbf;             base = (size_t)(b - 2048) * 2048; }
  else if (b < 2432) { src = Wkv; dst = wbf + 512 * 512; base = (size_t)(b - 2176) * 2048; }
  else               { src = Wo;  dst = wobf;            base = (size_t)(b - 2432) * 2048; }
  size_t i = base + (size_t)threadIdx.x * 8;
  float4 a = *(const float4*)(src + i);
  float4 c = *(const float4*)(src + i + 4);
  *(short8*)(dst + i) = cvt8(a, c);
}

// ---------------------------------------------------------------------------
// Kernel 1: QKV projection. 128x64 tile (grid 64x24 = 1536 blocks = 6/CU),
// BK=32, double-buffered gld16 staging, 1 barrier/iter. Each wave: 32 rows
// x 64 cols (acc[2][4]). Q pre-scaled by CLOG2_. Q,K -> [b,h,n,d];
// V -> [b,h,d,n]. Coalesced LDS epilogues (one head per block: c0 64-aligned).
// ---------------------------------------------------------------------------
__global__ __launch_bounds__(256) void qkv_gemm_kernel(
    const unsigned short* __restrict__ xbf, const unsigned short* __restrict__ wbf,
    unsigned short* __restrict__ qws, unsigned short* __restrict__ kws,
    unsigned short* __restrict__ vws)
{
  // bufs: [buf][A 4096 | B 2048] shorts (12288 total); epilogue overlays
  __shared__ __attribute__((aligned(16))) unsigned short sm[12288];

  const int t0 = blockIdx.x * 128;
  const int c0 = blockIdx.y * 64;                  // 0..1472 over [Wq|Wkv] rows
  const int cls = c0 >> 9;                         // 0=q 1=k 2=v (block-uniform)

  const int tid = threadIdx.x;
  const int wave = tid >> 6, lane = tid & 63;
  const int quad = lane >> 4, l16 = lane & 15;

  // staging source: row r_ (A: +64 for 2nd inst), granule gc = (tid&3)^(r_&3)
  const int r_ = tid >> 2;
  const int gc = (tid & 3) ^ (r_ & 3);
  const unsigned short* abase = xbf + (size_t)(t0 + r_) * IN_ + gc * 8;
  const unsigned short* bbase = wbf + (size_t)(c0 + r_) * IN_ + gc * 8;

  auto stage = [&](int k0, int buf) {
    unsigned short* sA = sm + buf * 6144;
    unsigned short* sB = sA + 4096;
    gld16(abase + k0,            sA + tid * 8);
    gld16(abase + 64 * IN_ + k0, sA + 2048 + tid * 8);
    gld16(bbase + k0,            sB + tid * 8);
  };

  f32x4 acc[2][4];
  #pragma unroll
  for (int i = 0; i < 2; i++)
    #pragma unroll
    for (int j = 0; j < 4; j++) acc[i][j] = (f32x4){0.f, 0.f, 0.f, 0.f};

  stage(0, 0);

  for (int kt = 0; kt < 16; kt++) {
    const int cur = kt & 1;
    __syncthreads();                       // tile kt landed; prev compute done
    if (kt + 1 < 16) stage((kt + 1) * 32, cur ^ 1);
    const unsigned short* sA = sm + cur * 6144;
    const unsigned short* sB = sA + 4096;
    const int sw = ((quad ^ (l16 & 3)) << 3);
    short8 af[2], bf[4];
    #pragma unroll
    for (int mi = 0; mi < 2; mi++)
      af[mi] = *(const short8*)&sA[(wave * 32 + mi * 16 + l16) * 32 + sw];
    #pragma unroll
    for (int ni = 0; ni < 4; ni++)
      bf[ni] = *(const short8*)&sB[(ni * 16 + l16) * 32 + sw];
    #pragma unroll
    for (int mi = 0; mi < 2; mi++)
      #pragma unroll
      for (int ni = 0; ni < 4; ni++)
        acc[mi][ni] = __builtin_amdgcn_mfma_f32_16x16x32_bf16(af[mi], bf[ni], acc[mi][ni], 0, 0, 0);
  }

  __syncthreads();  // main-loop LDS reads done; reuse sm for epilogue

  if (cls < 2) {
    // token-major C tile [128 tok][72], coalesced 64B-run readback (one head)
    const float qs = (cls == 0) ? CLOG2_ : 1.0f;   // fold softmax scale into Q
    #pragma unroll
    for (int mi = 0; mi < 2; mi++) {
      const int row0 = wave * 32 + mi * 16 + quad * 4;
      #pragma unroll
      for (int ni = 0; ni < 4; ni++) {
        const int col = ni * 16 + l16;
        #pragma unroll
        for (int r = 0; r < 4; r++)
          sm[(row0 + r) * 72 + col] = f2bf(acc[mi][ni][r] * qs);
      }
    }
    __syncthreads();
    const int row = tid >> 1, half = tid & 1;
    const int t = t0 + row, bb = t >> 11, nn = t & (N_ - 1);
    const int hh = (c0 & 511) >> 6;
    unsigned short* dst = ((cls == 0) ? qws : kws) +
                          ((size_t)(bb * H_ + hh) * N_ + nn) * D_ + half * 32;
    const unsigned short* srcp = &sm[row * 72 + half * 32];
    #pragma unroll
    for (int j = 0; j < 4; j++)
      *(uint4*)(dst + j * 8) = *(const uint4*)(srcp + j * 8);
  } else {
    // transposed C tile [64 col][136 tok], coalesced readback along n
    #pragma unroll
    for (int mi = 0; mi < 2; mi++) {
      const int tk = wave * 32 + mi * 16 + quad * 4;
      #pragma unroll
      for (int ni = 0; ni < 4; ni++) {
        const int col = ni * 16 + l16;
        bs4 pk4 = pack4(acc[mi][ni][0], acc[mi][ni][1], acc[mi][ni][2], acc[mi][ni][3]);
        *(bs4*)&sm[col * 136 + tk] = pk4;
      }
    }
    __syncthreads();
    const int col = tid >> 2, quarter = tid & 3;
    const int cw = (c0 - 1024) + col;
    const int hh = cw >> 6, dd = cw & 63;
    const int bb = t0 >> 11, n0 = (t0 & (N_ - 1)) + quarter * 32;
    unsigned short* dst = vws + ((size_t)(bb * H_ + hh) * D_ + dd) * N_ + n0;
    const unsigned short* srcp = &sm[col * 136 + quarter * 32];
    #pragma unroll
    for (int j = 0; j < 4; j++)
      *(uint4*)(dst + j * 8) = *(const uint4*)(srcp + j * 8);
  }
}

// ---------------------------------------------------------------------------
// Kernel 2: flash attention (unchanged from R9/R10: ~61 µs, MfmaUtil 40%).
// Transposed-S, unshifted exp2 (scale pre-folded into Q), q-tile 64,
// ones-MFMA l accumulation, global_load_lds dbuf staging, 1 barrier/iter.
// ---------------------------------------------------------------------------
__global__ __launch_bounds__(256) void attention_kernel(
    const unsigned short* __restrict__ qws,
    const unsigned short* __restrict__ kws,
    const unsigned short* __restrict__ vws,
    unsigned short* __restrict__ ows)
{
  __shared__ __attribute__((aligned(16))) unsigned short sm[2][8192];

  const int q0 = blockIdx.x * 64;
  const int bh = blockIdx.y;
  const int tid = threadIdx.x;
  const int wave = tid >> 6, lane = tid & 63;
  const int quad = lane >> 4, l16 = lane & 15;

  const unsigned short* qbase = qws + (size_t)bh * N_ * D_;
  const unsigned short* kbase = kws + (size_t)bh * N_ * D_;
  const unsigned short* vbase = vws + (size_t)bh * D_ * N_;

  const int qrow = q0 + wave * 16 + l16;
  short8 qf[2];
  #pragma unroll
  for (int kc = 0; kc < 2; kc++)
    qf[kc] = *(const short8*)(qbase + (size_t)qrow * D_ + kc * 32 + quad * 8);

  f32x4 ot[4];
  f32x4 otl;
  #pragma unroll
  for (int db = 0; db < 4; db++) ot[db] = (f32x4){0.f, 0.f, 0.f, 0.f};
  otl = (f32x4){0.f, 0.f, 0.f, 0.f};
  const bs4 ones4 = {(short)0x3F80, (short)0x3F80, (short)0x3F80, (short)0x3F80};

  const int r_ = tid >> 3;
  const int gc = (tid & 7) ^ (r_ & 7);
  const unsigned short* kst = kbase + (size_t)r_ * D_ + gc * 8;
  const unsigned short* vst = vbase + (size_t)r_ * N_ + gc * 8;

  {
    unsigned short* Ks = &sm[0][0];
    unsigned short* Vs = &sm[0][4096];
    gld16(kst,                 Ks + tid * 8);
    gld16(kst + 32 * D_,       Ks + 2048 + tid * 8);
    gld16(vst,                 Vs + tid * 8);
    gld16(vst + 32 * N_,       Vs + 2048 + tid * 8);
  }

  for (int kt = 0; kt < N_ / 64; kt++) {
    const int cur = kt & 1;
    __syncthreads();
    if (kt + 1 < N_ / 64) {
      const int k0 = (kt + 1) * 64;
      unsigned short* Ks = &sm[cur ^ 1][0];
      unsigned short* Vs = &sm[cur ^ 1][4096];
      gld16(kst + (size_t)k0 * D_,            Ks + tid * 8);
      gld16(kst + (size_t)(k0 + 32) * D_,     Ks + 2048 + tid * 8);
      gld16(vst + k0,                         Vs + tid * 8);
      gld16(vst + k0 + 32 * N_,               Vs + 2048 + tid * 8);
    }
    const unsigned short* Ks = &sm[cur][0];
    const unsigned short* Vs = &sm[cur][4096];

    f32x4 st[4];
    #pragma unroll
    for (int nb = 0; nb < 4; nb++) st[nb] = (f32x4){0.f, 0.f, 0.f, 0.f};
    #pragma unroll
    for (int kc = 0; kc < 2; kc++) {
      const int sw = (((kc * 4 + quad) ^ (l16 & 7)) << 3);
      #pragma unroll
      for (int nb = 0; nb < 4; nb++) {
        short8 kf = *(const short8*)&Ks[(nb * 16 + l16) * 64 + sw];
        st[nb] = __builtin_amdgcn_mfma_f32_16x16x32_bf16(kf, qf[kc], st[nb], 0, 0, 0);
      }
    }

    bs4 pf[4];
    #pragma unroll
    for (int nb = 0; nb < 4; nb++) {
      float p0 = __builtin_amdgcn_exp2f(st[nb][0]);
      float p1 = __builtin_amdgcn_exp2f(st[nb][1]);
      float p2 = __builtin_amdgcn_exp2f(st[nb][2]);
      float p3 = __builtin_amdgcn_exp2f(st[nb][3]);
      pf[nb] = pack4(p0, p1, p2, p3);
    }

    #pragma unroll
    for (int kb = 0; kb < 4; kb++) {
      const int g = kb * 2 + (quad >> 1);
      const int sub = (quad & 1) * 4;
      bs4 vf[4];
      #pragma unroll
      for (int db = 0; db < 4; db++)
        vf[db] = *(const bs4*)&Vs[(db * 16 + l16) * 64 + ((g ^ (l16 & 7)) << 3) + sub];
      #pragma unroll
      for (int db = 0; db < 4; db++)
        ot[db] = __builtin_amdgcn_mfma_f32_16x16x16bf16_1k(vf[db], pf[kb], ot[db], 0, 0, 0);
      otl = __builtin_amdgcn_mfma_f32_16x16x16bf16_1k(ones4, pf[kb], otl, 0, 0, 0);
    }
  }

  const float inv = 1.f / otl[0];
  __syncthreads();
  unsigned short* Os = (unsigned short*)sm;   // 64 x 72 overlay
  #pragma unroll
  for (int db = 0; db < 4; db++) {
    bs4 pk4 = pack4(ot[db][0] * inv, ot[db][1] * inv, ot[db][2] * inv, ot[db][3] * inv);
    *(bs4*)&Os[(wave * 16 + l16) * 72 + db * 16 + quad * 4] = pk4;
  }
  __syncthreads();
  const int b_ = bh >> 3, h_ = bh & 7;
  const int qloc = tid >> 2, chunk = tid & 3;
  unsigned short* dst = ows + ((size_t)b_ * N_ + q0 + qloc) * (H_ * D_) + h_ * 64 + chunk * 16;
  const unsigned short* srcp = &Os[qloc * 72 + chunk * 16];
  *(uint4*)dst = *(const uint4*)srcp;
  *(uint4*)(dst + 8) = *(const uint4*)(srcp + 8);
}

// ---------------------------------------------------------------------------
// Kernel 3: output projection. 64x64 tile (grid 128x8 = 1024 blocks = 4/CU),
// BK=32, double-buffered gld16 staging, 1 barrier/iter. Each wave: 16 rows
// x 64 cols (acc[4]). fp32 out + bias, 64B-run stores.
// ---------------------------------------------------------------------------
__global__ __launch_bounds__(256) void out_gemm_kernel(
    const unsigned short* __restrict__ ain, const unsigned short* __restrict__ wobf,
    const float* __restrict__ bo, float* __restrict__ y)
{
  // bufs: [buf][A 2048 | B 2048] shorts = 8192 total (16 KB)
  __shared__ __attribute__((aligned(16))) unsigned short sm[8192];

  const int t0 = blockIdx.x * 64;
  const int c0 = blockIdx.y * 64;
  const int tid = threadIdx.x;
  const int wave = tid >> 6, lane = tid & 63;
  const int quad = lane >> 4, l16 = lane & 15;

  const int r_ = tid >> 2;
  const int gc = (tid & 3) ^ (r_ & 3);
  const unsigned short* abase = ain  + (size_t)(t0 + r_) * IN_ + gc * 8;
  const unsigned short* bbase = wobf + (size_t)(c0 + r_) * IN_ + gc * 8;

  auto stage = [&](int k0, int buf) {
    unsigned short* sA = sm + buf * 4096;
    unsigned short* sB = sA + 2048;
    gld16(abase + k0, sA + tid * 8);
    gld16(bbase + k0, sB + tid * 8);
  };

  f32x4 acc[4];
  #pragma unroll
  for (int j = 0; j < 4; j++) acc[j] = (f32x4){0.f, 0.f, 0.f, 0.f};

  stage(0, 0);

  for (int kt = 0; kt < 16; kt++) {
    const int cur = kt & 1;
    __syncthreads();
    if (kt + 1 < 16) stage((kt + 1) * 32, cur ^ 1);
    const unsigned short* sA = sm + cur * 4096;
    const unsigned short* sB = sA + 2048;
    const int sw = ((quad ^ (l16 & 3)) << 3);
    short8 af = *(const short8*)&sA[(wave * 16 + l16) * 32 + sw];
    short8 bf[4];
    #pragma unroll
    for (int ni = 0; ni < 4; ni++)
      bf[ni] = *(const short8*)&sB[(ni * 16 + l16) * 32 + sw];
    #pragma unroll
    for (int ni = 0; ni < 4; ni++)
      acc[ni] = __builtin_amdgcn_mfma_f32_16x16x32_bf16(af, bf[ni], acc[ni], 0, 0, 0);
  }

  const int t = t0 + wave * 16 + quad * 4;
  #pragma unroll
  for (int ni = 0; ni < 4; ni++) {
    const int c = c0 + ni * 16 + l16;
    const float bias = bo[c];
    float* dst = y + (size_t)t * IN_ + c;
    dst[0]        = acc[ni][0] + bias;
    dst[IN_]      = acc[ni][1] + bias;
    dst[2 * IN_]  = acc[ni][2] + bias;
    dst[3 * IN_]  = acc[ni][3] + bias;
  }
}

extern "C" void kernel_launch(void* const* d_in, const int* in_sizes, int n_in,
                              void* d_out, int out_size, void* d_ws, size_t ws_size,
                              hipStream_t stream) {
  const float* x   = (const float*)d_in[0];
  const float* Wq  = (const float*)d_in[1];
  const float* Wkv = (const float*)d_in[2];
  const float* Wo  = (const float*)d_in[3];
  const float* bo  = (const float*)d_in[4];
  float* out = (float*)d_out;

  // ws (shorts): qws 4M | kws 4M | vws 4M | ows 4M | wbf 768K | wobf 256K  (~34 MB, proven)
  unsigned short* qws  = (unsigned short*)d_ws;
  unsigned short* kws  = qws + (size_t)TOK_ * 512;
  unsigned short* vws  = kws + (size_t)TOK_ * 512;
  unsigned short* ows  = vws + (size_t)TOK_ * 512;
  unsigned short* wbf  = ows + (size_t)TOK_ * 512;       // [Wq 512 | Wkv 1024] x 512
  unsigned short* wobf = wbf + (size_t)1536 * 512;
  unsigned short* xbf  = ows;  // alias: consumed by qkv before attention writes ows

  conv_all_kernel<<<dim3(2560), 256, 0, stream>>>(x, Wq, Wkv, Wo, xbf, wbf, wobf);
  qkv_gemm_kernel<<<dim3(TOK_ / 128, 1536 / 64), 256, 0, stream>>>(xbf, wbf, qws, kws, vws);
  attention_kernel<<<dim3(N_ / 64, B_ * H_), 256, 0, stream>>>(qws, kws, vws, ows);
  out_gemm_kernel<<<dim3(TOK_ / 64, 512 / 64), 256, 0, stream>>>(ows, wobf, bo, out);
}